// Round 1
// baseline (12234.375 us; speedup 1.0000x reference)
//
#include <hip/hip_runtime.h>

// ---------------------------------------------------------------------------
// LightGCN propagation: out = normalize(mean(emb, A emb, A^2 emb, A^3 emb))
// for two independent graphs (mashup: 100k nodes / 3.2M edges,
// api: 50k nodes / 1.6M edges), EMB_DIM = 64.
//
// Baseline strategy: COO SpMM with hardware fp32 atomics.
//   - 16 threads per edge, each owning a float4 slice of the 64-dim row.
//   - gather x[col] (256B contiguous per edge), scale by val, atomicAdd into
//     y[row].
// Elementwise copy/zero/axpy are float4-vectorized; final row-normalize is
// one 64-lane wave per row with shuffle reduction.
// ---------------------------------------------------------------------------

#define EMB_DIM 64

static inline int ceil_div_i(long long a, long long b) {
    return (int)((a + b - 1) / b);
}

__global__ void k_copy2(const float4* __restrict__ src,
                        float4* __restrict__ a,
                        float4* __restrict__ b, int n4) {
    int i = blockIdx.x * blockDim.x + threadIdx.x;
    if (i < n4) {
        float4 v = src[i];
        a[i] = v;
        b[i] = v;
    }
}

__global__ void k_zero(float4* __restrict__ p, int n4) {
    int i = blockIdx.x * blockDim.x + threadIdx.x;
    if (i < n4) p[i] = make_float4(0.f, 0.f, 0.f, 0.f);
}

__global__ void k_axpy(float4* __restrict__ acc, const float4* __restrict__ x,
                       int n4) {
    int i = blockIdx.x * blockDim.x + threadIdx.x;
    if (i < n4) {
        float4 a = acc[i];
        float4 v = x[i];
        a.x += v.x;
        a.y += v.y;
        a.z += v.z;
        a.w += v.w;
        acc[i] = a;
    }
}

// COO SpMM: y[rows[e], :] += vals[e] * x[cols[e], :]
// 16 threads per edge, thread sub-index handles dims [4*sub, 4*sub+3].
__global__ void k_spmm_atomic(const int* __restrict__ rows,
                              const int* __restrict__ cols,
                              const float* __restrict__ vals,
                              const float* __restrict__ x,
                              float* __restrict__ y, int n_edges) {
    unsigned tid = blockIdx.x * blockDim.x + threadIdx.x;
    unsigned e = tid >> 4;
    if (e >= (unsigned)n_edges) return;
    int sub = tid & 15;

    int r = rows[e];
    int c = cols[e];
    float v = vals[e];

    const float4 xv =
        *reinterpret_cast<const float4*>(x + ((size_t)c << 6) + (sub << 2));
    float* yp = y + ((size_t)r << 6) + (sub << 2);

    unsafeAtomicAdd(yp + 0, v * xv.x);
    unsafeAtomicAdd(yp + 1, v * xv.y);
    unsafeAtomicAdd(yp + 2, v * xv.z);
    unsafeAtomicAdd(yp + 3, v * xv.w);
}

// Row-wise: out = (acc * 0.25) / max(||acc * 0.25||_2, 1e-12)
// One 64-lane wave per row; block of 256 = 4 rows.
__global__ void k_normalize(float* __restrict__ out, int nrows) {
    int row = blockIdx.x * 4 + (threadIdx.x >> 6);
    if (row >= nrows) return;
    int lane = threadIdx.x & 63;

    size_t idx = ((size_t)row << 6) + lane;
    float v = out[idx] * 0.25f;
    float s = v * v;
#pragma unroll
    for (int off = 32; off; off >>= 1) s += __shfl_xor(s, off);
    float norm = fmaxf(sqrtf(s), 1e-12f);
    out[idx] = v / norm;
}

extern "C" void kernel_launch(void* const* d_in, const int* in_sizes, int n_in,
                              void* d_out, int out_size, void* d_ws,
                              size_t ws_size, hipStream_t stream) {
    const int* m_rows = (const int*)d_in[0];
    const int* m_cols = (const int*)d_in[1];
    const float* m_vals = (const float*)d_in[2];
    const int* a_rows = (const int*)d_in[3];
    const int* a_cols = (const int*)d_in[4];
    const float* a_vals = (const float*)d_in[5];
    const float* m_emb = (const float*)d_in[6];
    const float* a_emb = (const float*)d_in[7];

    int ne_m = in_sizes[0];
    int ne_a = in_sizes[3];
    int nm = in_sizes[6] / EMB_DIM;
    int na = in_sizes[7] / EMB_DIM;

    size_t elems_m = (size_t)nm * EMB_DIM;

    float* out_m = (float*)d_out;
    float* out_a = out_m + elems_m;

    // Workspace: two ping-pong buffers sized for the larger (mashup) graph;
    // the api pass runs after mashup finishes and reuses the same space.
    float* ws = (float*)d_ws;

    auto run_graph = [&](const int* rows, const int* cols, const float* vals,
                         const float* emb, float* out, float* buf0,
                         float* buf1, int nrows, int nedges) {
        size_t n = (size_t)nrows * EMB_DIM;
        int n4 = (int)(n / 4);
        int eb = 256;
        int eg = ceil_div_i(n4, eb);

        // acc (in out) = emb; cur (buf0) = emb
        k_copy2<<<eg, eb, 0, stream>>>((const float4*)emb, (float4*)out,
                                       (float4*)buf0, n4);

        float* cur = buf0;
        float* nxt = buf1;
        int spmm_grid = ceil_div_i((long long)nedges * 16, 256);
        for (int l = 0; l < 3; ++l) {
            k_zero<<<eg, eb, 0, stream>>>((float4*)nxt, n4);
            k_spmm_atomic<<<spmm_grid, 256, 0, stream>>>(rows, cols, vals, cur,
                                                         nxt, nedges);
            k_axpy<<<eg, eb, 0, stream>>>((float4*)out, (const float4*)nxt,
                                          n4);
            float* t = cur;
            cur = nxt;
            nxt = t;
        }
        k_normalize<<<ceil_div_i(nrows, 4), 256, 0, stream>>>(out, nrows);
    };

    float* buf0 = ws;
    float* buf1 = ws + elems_m;

    run_graph(m_rows, m_cols, m_vals, m_emb, out_m, buf0, buf1, nm, ne_m);
    run_graph(a_rows, a_cols, a_vals, a_emb, out_a, buf0, buf1, na, ne_a);
}

// Round 2
// 1359.624 us; speedup vs baseline: 8.9984x; 8.9984x over previous
//
#include <hip/hip_runtime.h>

// ---------------------------------------------------------------------------
// LightGCN propagation: out = normalize(mean(emb, A emb, A^2 emb, A^3 emb))
// for two graphs (mashup: 100k nodes / 3.2M edges, api: 50k / 1.6M), D=64.
//
// Round-1 strategy: atomic-free SpMM via on-device CSR build.
//   build:  histogram(rows) -> exclusive scan -> scatter packed (val,col)
//   spmm:   one 64-lane wave per row, lane = dim; serial loop over the row's
//           edges; x-gather is one coalesced 256B wave read; single coalesced
//           store per row. acc+= and final normalize fused into the SpMM.
// Falls back to the round-0 atomic path if ws_size is too small.
// ---------------------------------------------------------------------------

#define EMB_DIM 64
typedef unsigned long long ull;

static inline int cdiv(long long a, long long b) { return (int)((a + b - 1) / b); }

// ----------------------------- CSR build -----------------------------------

__global__ void k_zero_i(int* __restrict__ p, int n) {
    int i = blockIdx.x * blockDim.x + threadIdx.x;
    if (i < n) p[i] = 0;
}

__global__ void k_hist(const int* __restrict__ rows, int* __restrict__ counts,
                       int ne) {
    int i = blockIdx.x * blockDim.x + threadIdx.x;
    if (i < ne) atomicAdd(&counts[rows[i]], 1);
}

// Phase 1: per-1024-chunk exclusive scan; chunk sums to bsums.
#define SCAN_B 256
#define SCAN_E 1024
__global__ void k_scan1(const int* __restrict__ in, int n,
                        int* __restrict__ out, int* __restrict__ bsums) {
    __shared__ int lds[SCAN_B];
    int t = threadIdx.x;
    int base = blockIdx.x * SCAN_E + t * 4;
    int v[4];
    int s = 0;
#pragma unroll
    for (int j = 0; j < 4; ++j) {
        v[j] = (base + j < n) ? in[base + j] : 0;
        s += v[j];
    }
    lds[t] = s;
    __syncthreads();
    for (int off = 1; off < SCAN_B; off <<= 1) {
        int x = (t >= off) ? lds[t - off] : 0;
        __syncthreads();
        lds[t] += x;
        __syncthreads();
    }
    int run = lds[t] - s;  // exclusive prefix of this thread's chunk
    if (t == SCAN_B - 1) bsums[blockIdx.x] = lds[t];
#pragma unroll
    for (int j = 0; j < 4; ++j) {
        if (base + j < n) out[base + j] = run;
        run += v[j];
    }
}

// Phase 2: single-block exclusive scan of chunk sums (nb <= 1024).
__global__ void k_scan2(int* __restrict__ bsums, int nb) {
    __shared__ int lds[1024];
    int t = threadIdx.x;
    int v = (t < nb) ? bsums[t] : 0;
    lds[t] = v;
    __syncthreads();
    for (int off = 1; off < 1024; off <<= 1) {
        int x = (t >= off) ? lds[t - off] : 0;
        __syncthreads();
        lds[t] += x;
        __syncthreads();
    }
    if (t < nb) bsums[t] = lds[t] - v;  // exclusive
}

// Phase 3: add chunk offsets; copy to row_pos; cap row_ptr[n] = ne.
__global__ void k_scan3(int* __restrict__ row_ptr, int* __restrict__ row_pos,
                        const int* __restrict__ bsums, int n, int ne) {
    int i = blockIdx.x * blockDim.x + threadIdx.x;
    if (i < n) {
        int p = row_ptr[i] + bsums[i >> 10];
        row_ptr[i] = p;
        row_pos[i] = p;
    }
    if (i == 0) row_ptr[n] = ne;
}

__global__ void k_scatter(const int* __restrict__ rows,
                          const int* __restrict__ cols,
                          const float* __restrict__ vals, int ne,
                          int* __restrict__ row_pos, ull* __restrict__ ev) {
    int i = blockIdx.x * blockDim.x + threadIdx.x;
    if (i < ne) {
        int r = rows[i];
        int p = atomicAdd(&row_pos[r], 1);
        ull packed = ((ull)__float_as_uint(vals[i]) << 32) | (unsigned)cols[i];
        ev[p] = packed;
    }
}

// ----------------------------- CSR SpMM ------------------------------------
// One wave per row, lane = dim. sum = Σ val * x[col*64+lane].
//   FIRST:  acc = emb_row + sum ; nxt = sum
//   middle: acc += sum          ; nxt = sum
//   LAST:   a = (acc+sum)/4 ; normalize ; acc = a/||a||   (no nxt store)
template <bool FIRST, bool LAST>
__global__ void k_spmm_csr(const ull* __restrict__ ev,
                           const int* __restrict__ row_ptr,
                           const float* __restrict__ x,
                           float* __restrict__ nxt, float* __restrict__ acc,
                           const float* __restrict__ emb, int nrows) {
    int row = (int)((blockIdx.x * blockDim.x + threadIdx.x) >> 6);
    if (row >= nrows) return;
    int lane = threadIdx.x & 63;

    int s = row_ptr[row];
    int e = row_ptr[row + 1];

    float sum0 = 0.f, sum1 = 0.f;
    int j = s;
    for (; j + 2 <= e; j += 2) {
        ull p0 = ev[j];
        ull p1 = ev[j + 1];
        float x0 = x[((size_t)(unsigned)p0 << 6) | lane];
        float x1 = x[((size_t)(unsigned)p1 << 6) | lane];
        sum0 = fmaf(__uint_as_float((unsigned)(p0 >> 32)), x0, sum0);
        sum1 = fmaf(__uint_as_float((unsigned)(p1 >> 32)), x1, sum1);
    }
    if (j < e) {
        ull p0 = ev[j];
        float x0 = x[((size_t)(unsigned)p0 << 6) | lane];
        sum0 = fmaf(__uint_as_float((unsigned)(p0 >> 32)), x0, sum0);
    }
    float sum = sum0 + sum1;

    size_t idx = ((size_t)row << 6) | lane;
    if (FIRST) {
        float a = emb[idx] + sum;
        acc[idx] = a;
        nxt[idx] = sum;
    } else if (!LAST) {
        acc[idx] += sum;
        nxt[idx] = sum;
    } else {
        float a = (acc[idx] + sum) * 0.25f;
        float ss = a * a;
#pragma unroll
        for (int off = 32; off; off >>= 1) ss += __shfl_xor(ss, off);
        float nrm = fmaxf(sqrtf(ss), 1e-12f);
        acc[idx] = a / nrm;
    }
}

// ----------------------- fallback: atomic path -----------------------------

__global__ void k_copy2(const float4* __restrict__ src, float4* __restrict__ a,
                        float4* __restrict__ b, int n4) {
    int i = blockIdx.x * blockDim.x + threadIdx.x;
    if (i < n4) {
        float4 v = src[i];
        a[i] = v;
        b[i] = v;
    }
}

__global__ void k_zero(float4* __restrict__ p, int n4) {
    int i = blockIdx.x * blockDim.x + threadIdx.x;
    if (i < n4) p[i] = make_float4(0.f, 0.f, 0.f, 0.f);
}

__global__ void k_axpy(float4* __restrict__ acc, const float4* __restrict__ x,
                       int n4) {
    int i = blockIdx.x * blockDim.x + threadIdx.x;
    if (i < n4) {
        float4 a = acc[i];
        float4 v = x[i];
        a.x += v.x; a.y += v.y; a.z += v.z; a.w += v.w;
        acc[i] = a;
    }
}

__global__ void k_spmm_atomic(const int* __restrict__ rows,
                              const int* __restrict__ cols,
                              const float* __restrict__ vals,
                              const float* __restrict__ x,
                              float* __restrict__ y, int n_edges) {
    unsigned tid = blockIdx.x * blockDim.x + threadIdx.x;
    unsigned e = tid >> 4;
    if (e >= (unsigned)n_edges) return;
    int sub = tid & 15;
    int r = rows[e];
    int c = cols[e];
    float v = vals[e];
    const float4 xv =
        *reinterpret_cast<const float4*>(x + ((size_t)c << 6) + (sub << 2));
    float* yp = y + ((size_t)r << 6) + (sub << 2);
    unsafeAtomicAdd(yp + 0, v * xv.x);
    unsafeAtomicAdd(yp + 1, v * xv.y);
    unsafeAtomicAdd(yp + 2, v * xv.z);
    unsafeAtomicAdd(yp + 3, v * xv.w);
}

__global__ void k_normalize(float* __restrict__ out, int nrows) {
    int row = blockIdx.x * 4 + (threadIdx.x >> 6);
    if (row >= nrows) return;
    int lane = threadIdx.x & 63;
    size_t idx = ((size_t)row << 6) + lane;
    float v = out[idx] * 0.25f;
    float s = v * v;
#pragma unroll
    for (int off = 32; off; off >>= 1) s += __shfl_xor(s, off);
    float norm = fmaxf(sqrtf(s), 1e-12f);
    out[idx] = v / norm;
}

// ---------------------------------------------------------------------------

extern "C" void kernel_launch(void* const* d_in, const int* in_sizes, int n_in,
                              void* d_out, int out_size, void* d_ws,
                              size_t ws_size, hipStream_t stream) {
    const int* m_rows = (const int*)d_in[0];
    const int* m_cols = (const int*)d_in[1];
    const float* m_vals = (const float*)d_in[2];
    const int* a_rows = (const int*)d_in[3];
    const int* a_cols = (const int*)d_in[4];
    const float* a_vals = (const float*)d_in[5];
    const float* m_emb = (const float*)d_in[6];
    const float* a_emb = (const float*)d_in[7];

    int ne_m = in_sizes[0];
    int ne_a = in_sizes[3];
    int nm = in_sizes[6] / EMB_DIM;
    int na = in_sizes[7] / EMB_DIM;

    size_t elems_m = (size_t)nm * EMB_DIM;
    float* out_m = (float*)d_out;
    float* out_a = out_m + elems_m;

    // ws layout (sized for the larger mashup graph; api pass reuses it):
    char* w = (char*)d_ws;
    ull* ev = (ull*)w;              w += (size_t)ne_m * sizeof(ull);
    float* buf0 = (float*)w;        w += elems_m * sizeof(float);
    float* buf1 = (float*)w;        w += elems_m * sizeof(float);
    int* row_ptr = (int*)w;         w += ((size_t)nm + 1) * sizeof(int);
    int* row_pos = (int*)w;         w += (size_t)nm * sizeof(int);
    int* bsums = (int*)w;           w += 1024 * sizeof(int);
    size_t need = (size_t)(w - (char*)d_ws);

    if (ws_size >= need) {
        auto run_csr = [&](const int* rows, const int* cols, const float* vals,
                           const float* emb, float* out, int n, int ne) {
            // CSR build
            k_zero_i<<<cdiv(n, 256), 256, 0, stream>>>(row_pos, n);
            k_hist<<<cdiv(ne, 256), 256, 0, stream>>>(rows, row_pos, ne);
            int nb = cdiv(n, SCAN_E);
            k_scan1<<<nb, SCAN_B, 0, stream>>>(row_pos, n, row_ptr, bsums);
            k_scan2<<<1, 1024, 0, stream>>>(bsums, nb);
            k_scan3<<<cdiv(n, 256), 256, 0, stream>>>(row_ptr, row_pos, bsums,
                                                      n, ne);
            k_scatter<<<cdiv(ne, 256), 256, 0, stream>>>(rows, cols, vals, ne,
                                                         row_pos, ev);
            // 3 fused SpMM layers
            int g = cdiv(n, 4);  // 4 rows per 256-thread block
            k_spmm_csr<true, false><<<g, 256, 0, stream>>>(
                ev, row_ptr, emb, buf0, out, emb, n);
            k_spmm_csr<false, false><<<g, 256, 0, stream>>>(
                ev, row_ptr, buf0, buf1, out, nullptr, n);
            k_spmm_csr<false, true><<<g, 256, 0, stream>>>(
                ev, row_ptr, buf1, nullptr, out, nullptr, n);
        };
        run_csr(m_rows, m_cols, m_vals, m_emb, out_m, nm, ne_m);
        run_csr(a_rows, a_cols, a_vals, a_emb, out_a, na, ne_a);
        return;
    }

    // Fallback: round-0 atomic path (needs only 2 float buffers)
    float* fb0 = (float*)d_ws;
    float* fb1 = fb0 + elems_m;
    auto run_atomic = [&](const int* rows, const int* cols, const float* vals,
                          const float* emb, float* out, float* b0, float* b1,
                          int nrows, int nedges) {
        size_t n = (size_t)nrows * EMB_DIM;
        int n4 = (int)(n / 4);
        int eg = cdiv(n4, 256);
        k_copy2<<<eg, 256, 0, stream>>>((const float4*)emb, (float4*)out,
                                        (float4*)b0, n4);
        float* cur = b0;
        float* nxt = b1;
        int spmm_grid = cdiv((long long)nedges * 16, 256);
        for (int l = 0; l < 3; ++l) {
            k_zero<<<eg, 256, 0, stream>>>((float4*)nxt, n4);
            k_spmm_atomic<<<spmm_grid, 256, 0, stream>>>(rows, cols, vals, cur,
                                                         nxt, nedges);
            k_axpy<<<eg, 256, 0, stream>>>((float4*)out, (const float4*)nxt,
                                           n4);
            float* t = cur; cur = nxt; nxt = t;
        }
        k_normalize<<<cdiv(nrows, 4), 256, 0, stream>>>(out, nrows);
    };
    run_atomic(m_rows, m_cols, m_vals, m_emb, out_m, fb0, fb1, nm, ne_m);
    run_atomic(a_rows, a_cols, a_vals, a_emb, out_a, fb0, fb1, na, ne_a);
}